// Round 1
// baseline (8401.234 us; speedup 1.0000x reference)
//
#include <hip/hip_runtime.h>
#include <hip/hip_bf16.h>

// LSTM: B=64, T=512, I=256, H=1024, O=1.
// Persistent cooperative kernel: 256 blocks = 4 batch-groups x 64 unit-groups.
// R5: self-validating h words. Each h element is stored as a 32-bit word
//   bf16(h) | (tag<<16), tag = step+1. Consumers poll the data words directly
// (AND-reduce of high halves == t) — merges the flag round trip and the h
// round trip into ONE coherence event per step, and removes the producer's
// vmcnt(0) drain + flag store entirely (every word is self-contained).
// Back-pressure proof carries over from the flag scheme: a producer can only
// overwrite buffer p at step t+1 after observing tag t+1 from all 64 same-bg
// producers, which implies every same-bg block finished its step-t reads.
// Stale tags are 0 or t-2, both < t, and s<t => (s&t)!=t, so the AND check
// cannot pass spuriously.

typedef __bf16 bf16_t;
typedef bf16_t b16x8 __attribute__((ext_vector_type(8)));
typedef float  f32x4 __attribute__((ext_vector_type(4)));

#define TQ 512
#define IQ 256
#define HQ 1024

union U8 { b16x8 b; unsigned long long q[2]; unsigned short u[8]; unsigned d[4]; };

__device__ __forceinline__ float bf2f(unsigned short s) {
    return __uint_as_float(((unsigned)s) << 16);
}
__device__ __forceinline__ unsigned short f2bf(float f) {
    unsigned u = __float_as_uint(f);
    u += 0x7fff + ((u >> 16) & 1);   // RNE
    return (unsigned short)(u >> 16);
}
__device__ __forceinline__ b16x8 cvt84(float4 a, float4 b) {
    U8 r;
    r.u[0] = f2bf(a.x); r.u[1] = f2bf(a.y); r.u[2] = f2bf(a.z); r.u[3] = f2bf(a.w);
    r.u[4] = f2bf(b.x); r.u[5] = f2bf(b.y); r.u[6] = f2bf(b.z); r.u[7] = f2bf(b.w);
    return r.b;
}
// fast-rcp transcendentals: v_rcp_f32 instead of the full f32 divide expansion
__device__ __forceinline__ float frcp(float x) { return __builtin_amdgcn_rcpf(x); }
__device__ __forceinline__ float sigm(float x) {
    return frcp(1.f + __expf(-x));
}
__device__ __forceinline__ float tanh_f(float v) {
    float x = fminf(fmaxf(v, -15.f), 15.f);
    float e = __expf(2.f * x);
    return (e - 1.f) * frcp(e + 1.f);
}

__launch_bounds__(512, 2)
__global__ void lstm_persist(const float* __restrict__ x,
                             const float* __restrict__ Wih,
                             const float* __restrict__ Whh,
                             const float* __restrict__ bih,
                             const float* __restrict__ bhh,
                             const float* __restrict__ fcW,
                             const float* __restrict__ fcb,
                             float* __restrict__ out,
                             unsigned* __restrict__ hbuf) // [2][4][16][1024] u32: bf16|tag<<16
{
    __shared__ float red[2 * 8192];   // 64KB: double-buffered per-wave partials

    const int tid  = threadIdx.x;
    const int w    = tid >> 6;        // wave 0..7
    const int lane = tid & 63;
    const int bid  = blockIdx.x;
    const int bg   = bid & 3;         // batch group (16 batches)
    const int ug   = bid >> 2;        // unit group (16 hidden units)

    const int l16  = lane & 15;
    const int quad = lane >> 4;

    // ---- one-time: load weight fragments into registers (bf16) ----
    b16x8 wih[4];        // x part: this wave's x-kstep
    b16x8 whh[4][4];     // h part: 4 ksteps x 4 gates
    {
        const int koff = quad * 8;
        #pragma unroll
        for (int g = 0; g < 4; ++g) {
            int row = g * HQ + ug * 16 + l16;
            const float* p = Wih + (size_t)row * IQ + w * 32 + koff;
            float4 a = *(const float4*)p;
            float4 b = *(const float4*)(p + 4);
            wih[g] = cvt84(a, b);
            #pragma unroll
            for (int j = 0; j < 4; ++j) {
                int k0 = (w * 4 + j) * 32 + koff;
                const float* q = Whh + (size_t)row * HQ + k0;
                float4 c = *(const float4*)q;
                float4 e = *(const float4*)(q + 4);
                whh[j][g] = cvt84(c, e);
            }
        }
    }

    // wave0 epilogue state: lane owns (u = l16, batches quad*4 + r)
    float c_st[4] = {0.f, 0.f, 0.f, 0.f};
    float bias_r[4];
    if (w == 0) {
        #pragma unroll
        for (int g = 0; g < 4; ++g) {
            int gr = g * HQ + ug * 16 + l16;
            bias_r[g] = bih[gr] + bhh[gr];
        }
    }

    // hbuf[p][bg][b][u]: idx = p*65536 + bg*16384 + b*1024 + u
    // consumer: batch row b=l16, units k = w*128 + quad*8 + j*32 + {0..7}
    const unsigned* hrd0 = hbuf + ((size_t)bg * 16 + l16) * 1024 + w * 128 + quad * 8;
    // producer (wave0): u = ug*16 + l16 fixed, b = quad*4 + r
    unsigned*       hwr0 = hbuf + (size_t)bg * 16384 + ug * 16 + l16;

    // software-pipelined x load (step 0)
    const float* xbase = x + ((size_t)(bg * 16 + l16) * TQ) * IQ + w * 32 + quad * 8;
    float4 xa = *(const float4*)(xbase);
    float4 xb = *(const float4*)(xbase + 4);

    for (int t = 0; t < TQ; ++t) {
        const int p = t & 1;
        const unsigned* hp = hrd0 + (size_t)p * 65536;

        // ---- issue self-validating h loads (16 x 8B = 32 units/lane) ----
        unsigned long long d[16];
        #pragma unroll
        for (int j = 0; j < 4; ++j) {
            #pragma unroll
            for (int k = 0; k < 4; ++k)
                d[j * 4 + k] = __hip_atomic_load(
                    (const unsigned long long*)(hp + j * 32 + k * 2),
                    __ATOMIC_RELAXED, __HIP_MEMORY_SCOPE_AGENT);
        }

        // ---- h-independent shadow work under the load latency ----
        b16x8 ax = cvt84(xa, xb);
        f32x4 acc[4];
        #pragma unroll
        for (int g = 0; g < 4; ++g) {
            f32x4 z = {0.f, 0.f, 0.f, 0.f};
            acc[g] = __builtin_amdgcn_mfma_f32_16x16x32_bf16(ax, wih[g], z, 0, 0, 0);
        }

        // ---- poll: all 32 tags must equal t (AND-reduce of high halves) ----
        const unsigned need = (unsigned)t;
        for (;;) {
            unsigned m = 0xffffffffu;
            #pragma unroll
            for (int i = 0; i < 16; ++i) {
                m &= (unsigned)d[i];
                m &= (unsigned)(d[i] >> 32);
            }
            if (__all((m >> 16) == need)) break;
            #pragma unroll
            for (int j = 0; j < 4; ++j) {
                #pragma unroll
                for (int k = 0; k < 4; ++k)
                    d[j * 4 + k] = __hip_atomic_load(
                        (const unsigned long long*)(hp + j * 32 + k * 2),
                        __ATOMIC_RELAXED, __HIP_MEMORY_SCOPE_AGENT);
            }
        }

        // ---- unpack (v_perm pairs low halves) + h MFMAs ----
        #pragma unroll
        for (int j = 0; j < 4; ++j) {
            U8 r;
            #pragma unroll
            for (int mq = 0; mq < 4; ++mq)
                r.d[mq] = __builtin_amdgcn_perm((unsigned)(d[j * 4 + mq] >> 32),
                                                (unsigned)d[j * 4 + mq],
                                                0x05040100u);
            #pragma unroll
            for (int g = 0; g < 4; ++g)
                acc[g] = __builtin_amdgcn_mfma_f32_16x16x32_bf16(r.b, whh[j][g], acc[g], 0, 0, 0);
        }

        // ---- write per-wave partials (double-buffered) ----
        float* rb = &red[p * 8192];
        #pragma unroll
        for (int g = 0; g < 4; ++g)
            *(f32x4*)&rb[((w * 4 + g) * 64 + lane) * 4] = acc[g];
        __syncthreads();   // the single per-step block barrier

        if (w == 0) {
            // ---- reduce 8 K-partials ----
            f32x4 gv[4];
            #pragma unroll
            for (int g = 0; g < 4; ++g) {
                f32x4 s = *(const f32x4*)&rb[((0 * 4 + g) * 64 + lane) * 4];
                #pragma unroll
                for (int ww = 1; ww < 8; ++ww)
                    s += *(const f32x4*)&rb[((ww * 4 + g) * 64 + lane) * 4];
                gv[g] = s;
            }
            // ---- nonlinearities + tagged h stores (no drain, no flag) ----
            unsigned* hw = hwr0 + (size_t)(p ^ 1) * 65536;
            const unsigned tagv = (unsigned)(t + 1) << 16;
            #pragma unroll
            for (int r = 0; r < 4; ++r) {
                float gi = gv[0][r] + bias_r[0];
                float gf = gv[1][r] + bias_r[1];
                float gg = gv[2][r] + bias_r[2];
                float go = gv[3][r] + bias_r[3];
                float i_s = sigm(gi);
                float f_s = sigm(gf);
                float g_t = tanh_f(gg);
                float o_s = sigm(go);
                float c = f_s * c_st[r] + i_s * g_t;
                c_st[r] = c;
                float h = o_s * tanh_f(c);
                int b = quad * 4 + r;
                __hip_atomic_store(hw + (size_t)b * 1024,
                                   (unsigned)f2bf(h) | tagv,
                                   __ATOMIC_RELAXED, __HIP_MEMORY_SCOPE_AGENT);
            }
        }
        // x prefetch (all waves; overlaps next step's handoff latency)
        size_t nt = (t + 1 < TQ) ? (size_t)(t + 1) * IQ : (size_t)t * IQ;
        xa = *(const float4*)(xbase + nt);
        xb = *(const float4*)(xbase + nt + 4);
    }

    // ---- final projection: out = tanh(h_T) @ fcW^T + fcb (blocks 0..3) ----
    if (bid < 4) {
        const unsigned* hl = hbuf + (size_t)bg * 16384;   // T even -> buffer 0, tag TQ
        float fb = fcb[0];
        #pragma unroll
        for (int r = 0; r < 2; ++r) {
            int b = w * 2 + r;
            unsigned hv[16];
            for (;;) {
                #pragma unroll
                for (int j = 0; j < 16; ++j)
                    hv[j] = __hip_atomic_load(hl + (size_t)b * 1024 + j * 64 + lane,
                                              __ATOMIC_RELAXED, __HIP_MEMORY_SCOPE_AGENT);
                unsigned m = 0xffffffffu;
                #pragma unroll
                for (int j = 0; j < 16; ++j) m &= hv[j];
                if (__all((m >> 16) == (unsigned)TQ)) break;
            }
            float s = 0.f;
            #pragma unroll
            for (int j = 0; j < 16; ++j)
                s += tanh_f(bf2f((unsigned short)hv[j])) * fcW[j * 64 + lane];
            #pragma unroll
            for (int off = 32; off > 0; off >>= 1)
                s += __shfl_down(s, off);
            if (lane == 0) out[bg * 16 + b] = s + fb;
        }
    }
}

extern "C" void kernel_launch(void* const* d_in, const int* in_sizes, int n_in,
                              void* d_out, int out_size, void* d_ws, size_t ws_size,
                              hipStream_t stream) {
    (void)in_sizes; (void)n_in; (void)out_size; (void)ws_size;
    const float* x   = (const float*)d_in[0];
    const float* Wih = (const float*)d_in[1];
    const float* Whh = (const float*)d_in[2];
    const float* bih = (const float*)d_in[3];
    const float* bhh = (const float*)d_in[4];
    const float* fcW = (const float*)d_in[5];
    const float* fcb = (const float*)d_in[6];
    float* out = (float*)d_out;

    unsigned* hbuf = (unsigned*)d_ws;   // [2][4][16][1024] u32 = 524288 B

    hipMemsetAsync(d_ws, 0, 524288, stream);

    void* args[] = { &x, &Wih, &Whh, &bih, &bhh, &fcW, &fcb, &out, &hbuf };
    hipLaunchCooperativeKernel(reinterpret_cast<void*>(lstm_persist),
                               dim3(256), dim3(512), args, 0, stream);
}

// Round 2
// 3293.513 us; speedup vs baseline: 2.5508x; 2.5508x over previous
//
#include <hip/hip_runtime.h>
#include <hip/hip_bf16.h>

// LSTM: B=64, T=512, I=256, H=1024, O=1.
// Persistent cooperative kernel: 256 blocks = 4 batch-groups x 64 unit-groups.
// R6: bounded speculative tagged-h + flag fallback + parallel epilogue.
//  - h words are tagged u32: bf16(h) | (t+1)<<16 (R5 format).
//  - Consumer: issue tagged loads ONCE, self-validate tags (AND-reduce; a
//    stale tag s<t cannot satisfy (AND>>16)==t since AND==t => s superset of
//    t => s>=t). Hit = ONE coherence event, no flag involved. Miss = one
//    bounded retry, then R4-style flag poll + single ordered reload. Data
//    lines are read at most 3x/step -> no R5-style poll collapse.
//  - Producer epilogue parallelized across all 8 waves (2 batch rows each,
//    dup-half partial reduce + shfl_xor(16) combine). Per-wave flags (8 per
//    block in one 64B line) signal after per-wave vmcnt(0) drain -> no
//    second barrier on the critical path.
//  - Back-pressure: each block's 8 waves collectively validate all 64
//    producers (tags or flags) before barrier #1, which precedes the
//    block's own overwriting stores. So tag t+2 can never be observed
//    during a step-t check, and the AND-validation stays sound.

typedef __bf16 bf16_t;
typedef bf16_t b16x8 __attribute__((ext_vector_type(8)));
typedef float  f32x4 __attribute__((ext_vector_type(4)));

#define TQ 512
#define IQ 256
#define HQ 1024

union U8 { b16x8 b; unsigned long long q[2]; unsigned short u[8]; unsigned d[4]; };

__device__ __forceinline__ float bf2f(unsigned short s) {
    return __uint_as_float(((unsigned)s) << 16);
}
__device__ __forceinline__ unsigned short f2bf(float f) {
    unsigned u = __float_as_uint(f);
    u += 0x7fff + ((u >> 16) & 1);   // RNE
    return (unsigned short)(u >> 16);
}
__device__ __forceinline__ b16x8 cvt84(float4 a, float4 b) {
    U8 r;
    r.u[0] = f2bf(a.x); r.u[1] = f2bf(a.y); r.u[2] = f2bf(a.z); r.u[3] = f2bf(a.w);
    r.u[4] = f2bf(b.x); r.u[5] = f2bf(b.y); r.u[6] = f2bf(b.z); r.u[7] = f2bf(b.w);
    return r.b;
}
__device__ __forceinline__ float frcp(float x) { return __builtin_amdgcn_rcpf(x); }
__device__ __forceinline__ float sigm(float x) {
    return frcp(1.f + __expf(-x));
}
__device__ __forceinline__ float tanh_f(float v) {
    float x = fminf(fmaxf(v, -15.f), 15.f);
    float e = __expf(2.f * x);
    return (e - 1.f) * frcp(e + 1.f);
}

__device__ __forceinline__ void load16(unsigned long long* d, const unsigned* hp) {
    #pragma unroll
    for (int j = 0; j < 4; ++j) {
        #pragma unroll
        for (int k = 0; k < 4; ++k)
            d[j * 4 + k] = __hip_atomic_load(
                (const unsigned long long*)(hp + j * 32 + k * 2),
                __ATOMIC_RELAXED, __HIP_MEMORY_SCOPE_AGENT);
    }
}
__device__ __forceinline__ bool tags_ok(const unsigned long long* d, unsigned need) {
    unsigned m = 0xffffffffu;
    #pragma unroll
    for (int i = 0; i < 16; ++i) {
        m &= (unsigned)d[i];
        m &= (unsigned)(d[i] >> 32);
    }
    return __all((m >> 16) == need);
}

__launch_bounds__(512, 2)
__global__ void lstm_persist(const float* __restrict__ x,
                             const float* __restrict__ Wih,
                             const float* __restrict__ Whh,
                             const float* __restrict__ bih,
                             const float* __restrict__ bhh,
                             const float* __restrict__ fcW,
                             const float* __restrict__ fcb,
                             float* __restrict__ out,
                             unsigned* __restrict__ hbuf, // [2][4][16][1024] u32: bf16|tag<<16
                             unsigned* __restrict__ bar)  // [4][64][16] u32 per-wave flags
{
    __shared__ float red[2 * 8192];   // 64KB: double-buffered per-wave partials

    const int tid  = threadIdx.x;
    const int w    = tid >> 6;        // wave 0..7
    const int lane = tid & 63;
    const int bid  = blockIdx.x;
    const int bg   = bid & 3;         // batch group (16 batches)
    const int ug   = bid >> 2;        // unit group (16 hidden units)

    const int l16  = lane & 15;
    const int quad = lane >> 4;

    // ---- one-time: load weight fragments into registers (bf16) ----
    b16x8 wih[4];        // x part: this wave's x-kstep
    b16x8 whh[4][4];     // h part: 4 ksteps x 4 gates
    {
        const int koff = quad * 8;
        #pragma unroll
        for (int g = 0; g < 4; ++g) {
            int row = g * HQ + ug * 16 + l16;
            const float* p = Wih + (size_t)row * IQ + w * 32 + koff;
            float4 a = *(const float4*)p;
            float4 b = *(const float4*)(p + 4);
            wih[g] = cvt84(a, b);
            #pragma unroll
            for (int j = 0; j < 4; ++j) {
                int k0 = (w * 4 + j) * 32 + koff;
                const float* q = Whh + (size_t)row * HQ + k0;
                float4 c = *(const float4*)q;
                float4 e = *(const float4*)(q + 4);
                whh[j][g] = cvt84(c, e);
            }
        }
    }

    // ---- epilogue assignment (all waves): lane -> (u=l16, b=eb) ----
    const int eb    = 2 * w + ((lane >> 5) & 1);  // batch row 0..15
    const int dup   = (lane >> 4) & 1;            // partial-reduce half
    const int srcl  = (eb >> 2) * 16 + l16;       // source lane in partials
    const int rcomp = eb & 3;                     // f32x4 component
    float c_st = 0.f;
    float bias_g[4];
    #pragma unroll
    for (int g = 0; g < 4; ++g) {
        int gr = g * HQ + ug * 16 + l16;
        bias_g[g] = bih[gr] + bhh[gr];
    }

    // hbuf[p][bg][b][u]: idx = p*65536 + bg*16384 + b*1024 + u
    const unsigned* hrd0 = hbuf + ((size_t)bg * 16 + l16) * 1024 + w * 128 + quad * 8;
    unsigned*       hwr  = hbuf + (size_t)bg * 16384 + (size_t)eb * 1024 + ug * 16 + l16;

    // flags: bar[(bg*64 + block)*16 + wave]; one 64B line per producer block
    const unsigned* myfl = bar + ((size_t)(bg * 64 + (w * 8 + (lane >> 3))) * 16 + (lane & 7));
    unsigned*       wfl  = bar + ((size_t)(bg * 64 + ug) * 16 + w);

    // software-pipelined x load (step 0)
    const float* xbase = x + ((size_t)(bg * 16 + l16) * TQ) * IQ + w * 32 + quad * 8;
    float4 xa = *(const float4*)(xbase);
    float4 xb = *(const float4*)(xbase + 4);

    for (int t = 0; t < TQ; ++t) {
        const int p = t & 1;
        const unsigned* hp = hrd0 + (size_t)p * 65536;

        // ---- speculative tagged h loads (issued before the shadow work) ----
        unsigned long long d[16];
        load16(d, hp);

        // ---- h-independent shadow work under the load latency ----
        b16x8 ax = cvt84(xa, xb);
        f32x4 acc[4];
        #pragma unroll
        for (int g = 0; g < 4; ++g) {
            f32x4 z = {0.f, 0.f, 0.f, 0.f};
            acc[g] = __builtin_amdgcn_mfma_f32_16x16x32_bf16(ax, wih[g], z, 0, 0, 0);
        }

        // ---- validate; bounded retry; flag fallback ----
        const unsigned need = (unsigned)t;
        if (!tags_ok(d, need)) {
            load16(d, hp);                        // bounded retry #1
            if (!tags_ok(d, need)) {
                unsigned v = __hip_atomic_load(myfl, __ATOMIC_RELAXED,
                                               __HIP_MEMORY_SCOPE_AGENT);
                while (!__all(v >= need))
                    v = __hip_atomic_load(myfl, __ATOMIC_RELAXED,
                                          __HIP_MEMORY_SCOPE_AGENT);
                load16(d, hp);                    // ordered reload (fresh by R4 argument)
            }
        }

        // ---- unpack (v_perm pairs low halves) + h MFMAs ----
        #pragma unroll
        for (int j = 0; j < 4; ++j) {
            U8 r;
            #pragma unroll
            for (int mq = 0; mq < 4; ++mq)
                r.d[mq] = __builtin_amdgcn_perm((unsigned)(d[j * 4 + mq] >> 32),
                                                (unsigned)d[j * 4 + mq],
                                                0x05040100u);
            #pragma unroll
            for (int g = 0; g < 4; ++g)
                acc[g] = __builtin_amdgcn_mfma_f32_16x16x32_bf16(r.b, whh[j][g], acc[g], 0, 0, 0);
        }

        // ---- write per-wave partials (double-buffered) ----
        float* rb = &red[p * 8192];
        #pragma unroll
        for (int g = 0; g < 4; ++g)
            *(f32x4*)&rb[((w * 4 + g) * 64 + lane) * 4] = acc[g];
        __syncthreads();   // barrier #1 (orders reads of red[p] + back-pressure point)

        // ---- parallel epilogue: every wave handles 2 batch rows ----
        float s[4];
        #pragma unroll
        for (int g = 0; g < 4; ++g) {
            float a0 = rb[(((dup * 4 + 0) * 4 + g) * 64 + srcl) * 4 + rcomp]
                     + rb[(((dup * 4 + 1) * 4 + g) * 64 + srcl) * 4 + rcomp];
            float a1 = rb[(((dup * 4 + 2) * 4 + g) * 64 + srcl) * 4 + rcomp]
                     + rb[(((dup * 4 + 3) * 4 + g) * 64 + srcl) * 4 + rcomp];
            float as = a0 + a1;
            as += __shfl_xor(as, 16);            // combine dup halves
            s[g] = as;
        }
        {
            float gi = s[0] + bias_g[0];
            float gf = s[1] + bias_g[1];
            float gg = s[2] + bias_g[2];
            float go = s[3] + bias_g[3];
            float i_s = sigm(gi);
            float f_s = sigm(gf);
            float g_t = tanh_f(gg);
            float o_s = sigm(go);
            float c = f_s * c_st + i_s * g_t;
            c_st = c;
            float h = o_s * tanh_f(c);
            if (!dup)
                __hip_atomic_store(hwr + (size_t)(p ^ 1) * 65536,
                                   (unsigned)f2bf(h) | ((unsigned)(t + 1) << 16),
                                   __ATOMIC_RELAXED, __HIP_MEMORY_SCOPE_AGENT);
        }
        // drain this wave's h stores, then signal this wave's flag
        asm volatile("s_waitcnt vmcnt(0)" ::: "memory");
        if (lane == 0)
            __hip_atomic_store(wfl, (unsigned)(t + 1),
                               __ATOMIC_RELAXED, __HIP_MEMORY_SCOPE_AGENT);

        // x prefetch (after the drain so it doesn't extend it)
        size_t nt = (t + 1 < TQ) ? (size_t)(t + 1) * IQ : (size_t)t * IQ;
        xa = *(const float4*)(xbase + nt);
        xb = *(const float4*)(xbase + nt + 4);
    }

    // ---- final projection: out = tanh(h_T) @ fcW^T + fcb (blocks 0..3) ----
    if (bid < 4) {
        const unsigned* hl = hbuf + (size_t)bg * 16384;   // T even -> buffer 0, tag TQ
        float fb = fcb[0];
        #pragma unroll
        for (int r = 0; r < 2; ++r) {
            int b = w * 2 + r;
            unsigned hv[16];
            for (;;) {
                #pragma unroll
                for (int j = 0; j < 16; ++j)
                    hv[j] = __hip_atomic_load(hl + (size_t)b * 1024 + j * 64 + lane,
                                              __ATOMIC_RELAXED, __HIP_MEMORY_SCOPE_AGENT);
                unsigned m = 0xffffffffu;
                #pragma unroll
                for (int j = 0; j < 16; ++j) m &= hv[j];
                if (__all((m >> 16) == (unsigned)TQ)) break;
            }
            float sacc = 0.f;
            #pragma unroll
            for (int j = 0; j < 16; ++j)
                sacc += tanh_f(bf2f((unsigned short)hv[j])) * fcW[j * 64 + lane];
            #pragma unroll
            for (int off = 32; off > 0; off >>= 1)
                sacc += __shfl_down(sacc, off);
            if (lane == 0) out[bg * 16 + b] = sacc + fb;
        }
    }
}

extern "C" void kernel_launch(void* const* d_in, const int* in_sizes, int n_in,
                              void* d_out, int out_size, void* d_ws, size_t ws_size,
                              hipStream_t stream) {
    (void)in_sizes; (void)n_in; (void)out_size; (void)ws_size;
    const float* x   = (const float*)d_in[0];
    const float* Wih = (const float*)d_in[1];
    const float* Whh = (const float*)d_in[2];
    const float* bih = (const float*)d_in[3];
    const float* bhh = (const float*)d_in[4];
    const float* fcW = (const float*)d_in[5];
    const float* fcb = (const float*)d_in[6];
    float* out = (float*)d_out;

    unsigned* hbuf = (unsigned*)d_ws;                         // 524288 B
    unsigned* bar  = (unsigned*)((char*)d_ws + 524288);       // 16384 B

    hipMemsetAsync(d_ws, 0, 524288 + 16384, stream);

    void* args[] = { &x, &Wih, &Whh, &bih, &bhh, &fcW, &fcb, &out, &hbuf, &bar };
    hipLaunchCooperativeKernel(reinterpret_cast<void*>(lstm_persist),
                               dim3(256), dim3(512), args, 0, stream);
}

// Round 3
// 2955.651 us; speedup vs baseline: 2.8424x; 1.1143x over previous
//
#include <hip/hip_runtime.h>
#include <hip/hip_bf16.h>

// LSTM: B=64, T=512, I=256, H=1024, O=1.
// Persistent cooperative kernel: 256 blocks = 4 batch-groups x 64 unit-groups.
// R7: tagged h-words + sentinel-gated single bulk load; serial wave0 epilogue.
//  - h words: u32 = bf16(h) | (tag<<16), tag = step+1. Producer epilogue is
//    reduce -> activations -> 4 tagged stores. NO vmcnt drain, NO flag store:
//    the h word carries its own readiness. Removes 2 serialized coherence
//    latencies per step vs the R4 flag scheme.
//  - Consumer: poll a tiny SENTINEL (one tagged word per producer, 8 words
//    per wave per round — bounded like R4's flag poll, unlike R5's 8KB/wave
//    data-poll storm). Then ONE bulk tagged load; AND-validate tags; retry
//    only within the producer's store-completion-skew window (rare).
//  - Tag soundness: stale tags are 0 or t-2; AND(tags)==t => every tag has
//    all bits of t => every tag >= t => all tags == t.
//  - Back-pressure: block X overwrites buffer p^1 (tag t+1) only after its
//    8 waves validated all 64 producers' tag-t words in buffer p; a
//    producer's tag-t store is data-dependent on its own step-(t-1) reads
//    of p^1, so all same-bg reads of p^1 happen-before X's overwrite.
//  - Epilogue: R4's serial wave0 (pure ds_read_b128, zero bank conflicts).

typedef __bf16 bf16_t;
typedef bf16_t b16x8 __attribute__((ext_vector_type(8)));
typedef float  f32x4 __attribute__((ext_vector_type(4)));

#define TQ 512
#define IQ 256
#define HQ 1024

union U8 { b16x8 b; unsigned long long q[2]; unsigned short u[8]; unsigned d[4]; };

__device__ __forceinline__ float bf2f(unsigned short s) {
    return __uint_as_float(((unsigned)s) << 16);
}
__device__ __forceinline__ unsigned short f2bf(float f) {
    unsigned u = __float_as_uint(f);
    u += 0x7fff + ((u >> 16) & 1);   // RNE
    return (unsigned short)(u >> 16);
}
__device__ __forceinline__ b16x8 cvt84(float4 a, float4 b) {
    U8 r;
    r.u[0] = f2bf(a.x); r.u[1] = f2bf(a.y); r.u[2] = f2bf(a.z); r.u[3] = f2bf(a.w);
    r.u[4] = f2bf(b.x); r.u[5] = f2bf(b.y); r.u[6] = f2bf(b.z); r.u[7] = f2bf(b.w);
    return r.b;
}
__device__ __forceinline__ float frcp(float x) { return __builtin_amdgcn_rcpf(x); }
__device__ __forceinline__ float sigm(float x) {
    return frcp(1.f + __expf(-x));
}
__device__ __forceinline__ float tanh_f(float v) {
    float x = fminf(fmaxf(v, -15.f), 15.f);
    float e = __expf(2.f * x);
    return (e - 1.f) * frcp(e + 1.f);
}

__device__ __forceinline__ void load16(unsigned long long* d, const unsigned* hp) {
    #pragma unroll
    for (int j = 0; j < 4; ++j) {
        #pragma unroll
        for (int k = 0; k < 4; ++k)
            d[j * 4 + k] = __hip_atomic_load(
                (const unsigned long long*)(hp + j * 32 + k * 2),
                __ATOMIC_RELAXED, __HIP_MEMORY_SCOPE_AGENT);
    }
}
__device__ __forceinline__ bool tags_ok(const unsigned long long* d, unsigned need) {
    unsigned m = 0xffffffffu;
    #pragma unroll
    for (int i = 0; i < 16; ++i) {
        m &= (unsigned)d[i];
        m &= (unsigned)(d[i] >> 32);
    }
    return __all((m >> 16) == need);
}

__launch_bounds__(512, 2)
__global__ void lstm_persist(const float* __restrict__ x,
                             const float* __restrict__ Wih,
                             const float* __restrict__ Whh,
                             const float* __restrict__ bih,
                             const float* __restrict__ bhh,
                             const float* __restrict__ fcW,
                             const float* __restrict__ fcb,
                             float* __restrict__ out,
                             unsigned* __restrict__ hbuf) // [2][4][16][1024] u32: bf16|tag<<16
{
    __shared__ float red[2 * 8192];   // 64KB: double-buffered per-wave partials

    const int tid  = threadIdx.x;
    const int w    = tid >> 6;        // wave 0..7
    const int lane = tid & 63;
    const int bid  = blockIdx.x;
    const int bg   = bid & 3;         // batch group (16 batches)
    const int ug   = bid >> 2;        // unit group (16 hidden units)

    const int l16  = lane & 15;
    const int quad = lane >> 4;

    // ---- one-time: load weight fragments into registers (bf16) ----
    b16x8 wih[4];        // x part: this wave's x-kstep
    b16x8 whh[4][4];     // h part: 4 ksteps x 4 gates
    {
        const int koff = quad * 8;
        #pragma unroll
        for (int g = 0; g < 4; ++g) {
            int row = g * HQ + ug * 16 + l16;
            const float* p = Wih + (size_t)row * IQ + w * 32 + koff;
            float4 a = *(const float4*)p;
            float4 b = *(const float4*)(p + 4);
            wih[g] = cvt84(a, b);
            #pragma unroll
            for (int j = 0; j < 4; ++j) {
                int k0 = (w * 4 + j) * 32 + koff;
                const float* q = Whh + (size_t)row * HQ + k0;
                float4 c = *(const float4*)q;
                float4 e = *(const float4*)(q + 4);
                whh[j][g] = cvt84(c, e);
            }
        }
    }

    // wave0 epilogue state: lane owns (u = l16, batches quad*4 + r)
    float c_st[4] = {0.f, 0.f, 0.f, 0.f};
    float bias_r[4];
    if (w == 0) {
        #pragma unroll
        for (int g = 0; g < 4; ++g) {
            int gr = g * HQ + ug * 16 + l16;
            bias_r[g] = bih[gr] + bhh[gr];
        }
    }

    // hbuf[p][bg][b][u]: idx = p*65536 + bg*16384 + b*1024 + u
    // consumer bulk: batch row b=l16, units w*128 + j*32 + quad*8 + {0..7}
    const unsigned* hrd0 = hbuf + ((size_t)bg * 16 + l16) * 1024 + w * 128 + quad * 8;
    // sentinel: one word of producer (w*8 + lane&7): batch 0, unit ug'*16
    const unsigned* sen0 = hbuf + (size_t)bg * 16384 + (size_t)(w * 8 + (lane & 7)) * 16;
    // producer (wave0): u = ug*16 + l16 fixed, b = quad*4 + r
    unsigned*       hwr0 = hbuf + (size_t)bg * 16384 + ug * 16 + l16;

    // software-pipelined x load (step 0)
    const float* xbase = x + ((size_t)(bg * 16 + l16) * TQ) * IQ + w * 32 + quad * 8;
    float4 xa = *(const float4*)(xbase);
    float4 xb = *(const float4*)(xbase + 4);

    for (int t = 0; t < TQ; ++t) {
        const int p = t & 1;
        const unsigned* hp = hrd0 + (size_t)p * 65536;
        const unsigned* sp = sen0 + (size_t)p * 65536;

        // ---- h-independent shadow work ----
        b16x8 ax = cvt84(xa, xb);
        f32x4 acc[4];
        #pragma unroll
        for (int g = 0; g < 4; ++g) {
            f32x4 z = {0.f, 0.f, 0.f, 0.f};
            acc[g] = __builtin_amdgcn_mfma_f32_16x16x32_bf16(ax, wih[g], z, 0, 0, 0);
        }

        // ---- sentinel poll: one tagged word per producer (8 per wave) ----
        const unsigned need = (unsigned)t;
        {
            unsigned v = __hip_atomic_load(sp, __ATOMIC_RELAXED,
                                           __HIP_MEMORY_SCOPE_AGENT);
            while (!__all((v >> 16) == need))
                v = __hip_atomic_load(sp, __ATOMIC_RELAXED,
                                      __HIP_MEMORY_SCOPE_AGENT);
        }

        // ---- single bulk tagged load + validate (retry only in skew window) ----
        unsigned long long d[16];
        load16(d, hp);
        while (!tags_ok(d, need))
            load16(d, hp);

        // ---- unpack (v_perm pairs low halves) + h MFMAs ----
        #pragma unroll
        for (int j = 0; j < 4; ++j) {
            U8 r;
            #pragma unroll
            for (int mq = 0; mq < 4; ++mq)
                r.d[mq] = __builtin_amdgcn_perm((unsigned)(d[j * 4 + mq] >> 32),
                                                (unsigned)d[j * 4 + mq],
                                                0x05040100u);
            #pragma unroll
            for (int g = 0; g < 4; ++g)
                acc[g] = __builtin_amdgcn_mfma_f32_16x16x32_bf16(r.b, whh[j][g], acc[g], 0, 0, 0);
        }

        // ---- write per-wave partials (double-buffered) ----
        float* rb = &red[p * 8192];
        #pragma unroll
        for (int g = 0; g < 4; ++g)
            *(f32x4*)&rb[((w * 4 + g) * 64 + lane) * 4] = acc[g];
        __syncthreads();   // the single per-step block barrier

        if (w == 0) {
            // ---- reduce 8 K-partials (pure ds_read_b128, conflict-free) ----
            f32x4 gv[4];
            #pragma unroll
            for (int g = 0; g < 4; ++g) {
                f32x4 s = *(const f32x4*)&rb[((0 * 4 + g) * 64 + lane) * 4];
                #pragma unroll
                for (int ww = 1; ww < 8; ++ww)
                    s += *(const f32x4*)&rb[((ww * 4 + g) * 64 + lane) * 4];
                gv[g] = s;
            }
            // ---- nonlinearities + tagged h stores (no drain, no flag) ----
            unsigned* hw = hwr0 + (size_t)(p ^ 1) * 65536;
            const unsigned tagv = (unsigned)(t + 1) << 16;
            #pragma unroll
            for (int r = 0; r < 4; ++r) {
                float gi = gv[0][r] + bias_r[0];
                float gf = gv[1][r] + bias_r[1];
                float gg = gv[2][r] + bias_r[2];
                float go = gv[3][r] + bias_r[3];
                float i_s = sigm(gi);
                float f_s = sigm(gf);
                float g_t = tanh_f(gg);
                float o_s = sigm(go);
                float c = f_s * c_st[r] + i_s * g_t;
                c_st[r] = c;
                float h = o_s * tanh_f(c);
                int b = quad * 4 + r;
                __hip_atomic_store(hw + (size_t)b * 1024,
                                   (unsigned)f2bf(h) | tagv,
                                   __ATOMIC_RELAXED, __HIP_MEMORY_SCOPE_AGENT);
            }
        }
        // x prefetch (all waves; overlaps the next step's handoff latency)
        size_t nt = (t + 1 < TQ) ? (size_t)(t + 1) * IQ : (size_t)t * IQ;
        xa = *(const float4*)(xbase + nt);
        xb = *(const float4*)(xbase + nt + 4);
    }

    // ---- final projection: out = tanh(h_T) @ fcW^T + fcb (blocks 0..3) ----
    if (bid < 4) {
        const unsigned* hl = hbuf + (size_t)bg * 16384;   // T even -> buffer 0, tag TQ
        float fb = fcb[0];
        #pragma unroll
        for (int r = 0; r < 2; ++r) {
            int b = w * 2 + r;
            unsigned hv[16];
            for (;;) {
                #pragma unroll
                for (int j = 0; j < 16; ++j)
                    hv[j] = __hip_atomic_load(hl + (size_t)b * 1024 + j * 64 + lane,
                                              __ATOMIC_RELAXED, __HIP_MEMORY_SCOPE_AGENT);
                unsigned m = 0xffffffffu;
                #pragma unroll
                for (int j = 0; j < 16; ++j) m &= hv[j];
                if (__all((m >> 16) == (unsigned)TQ)) break;
            }
            float sacc = 0.f;
            #pragma unroll
            for (int j = 0; j < 16; ++j)
                sacc += tanh_f(bf2f((unsigned short)hv[j])) * fcW[j * 64 + lane];
            #pragma unroll
            for (int off = 32; off > 0; off >>= 1)
                sacc += __shfl_down(sacc, off);
            if (lane == 0) out[bg * 16 + b] = sacc + fb;
        }
    }
}

extern "C" void kernel_launch(void* const* d_in, const int* in_sizes, int n_in,
                              void* d_out, int out_size, void* d_ws, size_t ws_size,
                              hipStream_t stream) {
    (void)in_sizes; (void)n_in; (void)out_size; (void)ws_size;
    const float* x   = (const float*)d_in[0];
    const float* Wih = (const float*)d_in[1];
    const float* Whh = (const float*)d_in[2];
    const float* bih = (const float*)d_in[3];
    const float* bhh = (const float*)d_in[4];
    const float* fcW = (const float*)d_in[5];
    const float* fcb = (const float*)d_in[6];
    float* out = (float*)d_out;

    unsigned* hbuf = (unsigned*)d_ws;   // [2][4][16][1024] u32 = 524288 B

    hipMemsetAsync(d_ws, 0, 524288, stream);

    void* args[] = { &x, &Wih, &Whh, &bih, &bhh, &fcW, &fcb, &out, &hbuf };
    hipLaunchCooperativeKernel(reinterpret_cast<void*>(lstm_persist),
                               dim3(256), dim3(512), args, 0, stream);
}

// Round 4
// 2250.031 us; speedup vs baseline: 3.7338x; 1.3136x over previous
//
#include <hip/hip_runtime.h>
#include <hip/hip_bf16.h>

// LSTM: B=64, T=512, I=256, H=1024, O=1.
// Persistent cooperative kernel: 256 blocks = 4 batch-groups x 64 unit-groups.
// R8 = R4 skeleton (bf16 h + dedicated flag lines + drain->flag->poll->load)
//      + PARALLEL EPILOGUE across all 8 waves, conflict-free:
//  - partials LDS layout [w][g][u=16][b pad 20]: MFMA acc f32x4 (4 batches,
//    one unit) = one aligned ds_write_b128; banks uniform. Epilogue reads
//    scalar b32 (20*u + b spreads 16 banks, ~4-way worst) — not R6's 8-way
//    f32x4-component scatter (100M conflicts).
//  - single-buffered red (40KB) + 2nd barrier placed right after MFMAs
//    (waves arrive together; replaces the 40KB double buffer).
//  - each wave reduces + activates 2 batch rows (4 transcendentals/lane vs
//    16 serial), stores 2 h lines, drains (2 lines, fast), signals its own
//    flag word. Consumer polls 8 producers x 8 waves with 64 lanes on the
//    same dedicated flag lines as R4.
// Back-pressure: any flag t+1 from a block implies that block passed its
// barrier B at step t, which implies all 8 of its waves finished reading
// h buffer p at step t. A producer overwrites p only after seeing ALL
// 64 blocks' x 8 waves' flags >= t+1. Same argument as R4.

typedef __bf16 bf16_t;
typedef bf16_t b16x8 __attribute__((ext_vector_type(8)));
typedef float  f32x4 __attribute__((ext_vector_type(4)));

#define TQ 512
#define IQ 256
#define HQ 1024

// partials: [w][g][u=16][b padded to 20] floats = 40960 B
#define RED(w,g,u,b) (((((w)*4 + (g))*16 + (u))*20) + (b))

union U8 { b16x8 b; unsigned long long q[2]; unsigned short u[8]; };

__device__ __forceinline__ float bf2f(unsigned short s) {
    return __uint_as_float(((unsigned)s) << 16);
}
__device__ __forceinline__ unsigned short f2bf(float f) {
    unsigned u = __float_as_uint(f);
    u += 0x7fff + ((u >> 16) & 1);   // RNE
    return (unsigned short)(u >> 16);
}
__device__ __forceinline__ b16x8 cvt84(float4 a, float4 b) {
    U8 r;
    r.u[0] = f2bf(a.x); r.u[1] = f2bf(a.y); r.u[2] = f2bf(a.z); r.u[3] = f2bf(a.w);
    r.u[4] = f2bf(b.x); r.u[5] = f2bf(b.y); r.u[6] = f2bf(b.z); r.u[7] = f2bf(b.w);
    return r.b;
}
// agent-scope 16B load as 2x8B atomic loads — bypasses non-coherent L1/L2
__device__ __forceinline__ b16x8 load_h16(const unsigned short* p) {
    U8 r;
    r.q[0] = __hip_atomic_load((const unsigned long long*)p,
                               __ATOMIC_RELAXED, __HIP_MEMORY_SCOPE_AGENT);
    r.q[1] = __hip_atomic_load((const unsigned long long*)(p + 4),
                               __ATOMIC_RELAXED, __HIP_MEMORY_SCOPE_AGENT);
    return r.b;
}
__device__ __forceinline__ float frcp(float x) { return __builtin_amdgcn_rcpf(x); }
__device__ __forceinline__ float sigm(float x) {
    return frcp(1.f + __expf(-x));
}
__device__ __forceinline__ float tanh_f(float v) {
    float x = fminf(fmaxf(v, -15.f), 15.f);
    float e = __expf(2.f * x);
    return (e - 1.f) * frcp(e + 1.f);
}

__launch_bounds__(512, 2)
__global__ void lstm_persist(const float* __restrict__ x,
                             const float* __restrict__ Wih,
                             const float* __restrict__ Whh,
                             const float* __restrict__ bih,
                             const float* __restrict__ bhh,
                             const float* __restrict__ fcW,
                             const float* __restrict__ fcb,
                             float* __restrict__ out,
                             unsigned short* __restrict__ hbuf, // [2][4][16][1024] bf16
                             unsigned int* __restrict__ bar)    // [4][64][16] u32: per-wave flags
{
    __shared__ float red[8 * 4 * 16 * 20];   // 40 KB, single-buffered

    const int tid  = threadIdx.x;
    const int w    = tid >> 6;        // wave 0..7
    const int lane = tid & 63;
    const int bid  = blockIdx.x;
    const int bg   = bid & 3;         // batch group (16 batches)
    const int ug   = bid >> 2;        // unit group (16 hidden units)

    const int l16  = lane & 15;
    const int quad = lane >> 4;

    // ---- one-time: load weight fragments into registers (bf16) ----
    b16x8 wih[4];        // x part: this wave's x-kstep
    b16x8 whh[4][4];     // h part: 4 ksteps x 4 gates
    {
        const int koff = quad * 8;
        #pragma unroll
        for (int g = 0; g < 4; ++g) {
            int row = g * HQ + ug * 16 + l16;
            const float* p = Wih + (size_t)row * IQ + w * 32 + koff;
            float4 a = *(const float4*)p;
            float4 b = *(const float4*)(p + 4);
            wih[g] = cvt84(a, b);
            #pragma unroll
            for (int j = 0; j < 4; ++j) {
                int k0 = (w * 4 + j) * 32 + koff;
                const float* q = Whh + (size_t)row * HQ + k0;
                float4 c = *(const float4*)q;
                float4 e = *(const float4*)(q + 4);
                whh[j][g] = cvt84(c, e);
            }
        }
    }

    // ---- epilogue lane assignment: (b = eb, u = l16), dup pairs xor-16 ----
    const int hi  = (lane >> 5) & 1;
    const int eb  = 2 * w + hi;          // batch row handled by this lane
    const int dup = (lane >> 4) & 1;     // partial-sum half (ww 0-3 vs 4-7)
    float c_st = 0.f;                    // cell state for (eb, u=l16)
    float bias_g[4];
    #pragma unroll
    for (int g = 0; g < 4; ++g) {
        int gr = g * HQ + ug * 16 + l16;
        bias_g[g] = bih[gr] + bhh[gr];
    }

    // hbuf[p][bg][b][u] bf16
    const unsigned short* hrd0 = hbuf + ((size_t)bg * 16 + l16) * HQ;  // consumer row base
    unsigned short*       hwr0 = hbuf + (size_t)bg * 16 * HQ + (size_t)eb * HQ + ug * 16 + l16;

    // flags: bar[(bg*64 + prod)*16 + wave]; one 64B line per producer block
    const unsigned int* myfl = bar + ((size_t)(bg * 64 + w * 8 + (lane >> 3)) * 16 + (lane & 7));
    unsigned int*       wfl  = bar + ((size_t)(bg * 64 + ug) * 16 + w);

    // software-pipelined x load (step 0)
    const float* xbase = x + ((size_t)(bg * 16 + l16) * TQ) * IQ + w * 32 + quad * 8;
    float4 xa = *(const float4*)(xbase);
    float4 xb = *(const float4*)(xbase + 4);

    for (int t = 0; t < TQ; ++t) {
        const int p = t & 1;

        // ---- h-independent shadow work ----
        b16x8 ax = cvt84(xa, xb);
        f32x4 acc[4];
        #pragma unroll
        for (int g = 0; g < 4; ++g) {
            f32x4 z = {0.f, 0.f, 0.f, 0.f};
            acc[g] = __builtin_amdgcn_mfma_f32_16x16x32_bf16(ax, wih[g], z, 0, 0, 0);
        }

        // ---- poll this K-slice's 8 producers x 8 waves (64 lanes) ----
        const unsigned need = (unsigned)t;
        {
            unsigned v = __hip_atomic_load(myfl, __ATOMIC_RELAXED,
                                           __HIP_MEMORY_SCOPE_AGENT);
            while (!__all(v >= need))
                v = __hip_atomic_load(myfl, __ATOMIC_RELAXED,
                                      __HIP_MEMORY_SCOPE_AGENT);
        }

        // ---- h A-fragments + h MFMAs ----
        const unsigned short* hread = hrd0 + (size_t)p * (4 * 16 * HQ);
        b16x8 ah[4];
        #pragma unroll
        for (int j = 0; j < 4; ++j)
            ah[j] = load_h16(hread + (w * 4 + j) * 32 + quad * 8);
        #pragma unroll
        for (int j = 0; j < 4; ++j) {
            #pragma unroll
            for (int g = 0; g < 4; ++g)
                acc[g] = __builtin_amdgcn_mfma_f32_16x16x32_bf16(ah[j], whh[j][g], acc[g], 0, 0, 0);
        }

        // ---- barrier A: previous step's epilogue reads are complete ----
        __syncthreads();

        // ---- write partials: one aligned ds_write_b128 per (lane, gate) ----
        #pragma unroll
        for (int g = 0; g < 4; ++g)
            *(f32x4*)&red[RED(w, g, l16, quad * 4)] = acc[g];
        __syncthreads();   // barrier B: partials visible to all waves

        // ---- parallel epilogue: all 8 waves, 2 batch rows each ----
        float s[4];
        #pragma unroll
        for (int g = 0; g < 4; ++g) {
            float a0 = red[RED(dup * 4 + 0, g, l16, eb)]
                     + red[RED(dup * 4 + 1, g, l16, eb)];
            float a1 = red[RED(dup * 4 + 2, g, l16, eb)]
                     + red[RED(dup * 4 + 3, g, l16, eb)];
            float as = a0 + a1;
            as += __shfl_xor(as, 16);      // combine dup halves
            s[g] = as;
        }
        {
            float gi = s[0] + bias_g[0];
            float gf = s[1] + bias_g[1];
            float gg = s[2] + bias_g[2];
            float go = s[3] + bias_g[3];
            float i_s = sigm(gi);
            float f_s = sigm(gf);
            float g_t = tanh_f(gg);
            float o_s = sigm(go);
            float c = f_s * c_st + i_s * g_t;
            c_st = c;
            float h = o_s * tanh_f(c);
            if (!dup)
                __hip_atomic_store(hwr0 + (size_t)(p ^ 1) * (4 * 16 * HQ), f2bf(h),
                                   __ATOMIC_RELAXED, __HIP_MEMORY_SCOPE_AGENT);
        }
        // per-wave drain (2 store lines) then per-wave flag
        asm volatile("s_waitcnt vmcnt(0)" ::: "memory");
        if (lane == 0)
            __hip_atomic_store(wfl, (unsigned)(t + 1),
                               __ATOMIC_RELAXED, __HIP_MEMORY_SCOPE_AGENT);

        // x prefetch (after the drain so it doesn't extend it)
        size_t nt = (t + 1 < TQ) ? (size_t)(t + 1) * IQ : (size_t)t * IQ;
        xa = *(const float4*)(xbase + nt);
        xb = *(const float4*)(xbase + nt + 4);
    }

    // ---- final projection: out = tanh(h_T) @ fcW^T + fcb (blocks 0..3) ----
    if (bid < 4) {
        // wait for all 64 producers x 8 waves
        #pragma unroll
        for (int pb = 0; pb < 8; ++pb) {
            const unsigned int* pf = bar + ((size_t)(bg * 64 + pb * 8 + (lane >> 3)) * 16 + (lane & 7));
            unsigned v = __hip_atomic_load(pf, __ATOMIC_RELAXED,
                                           __HIP_MEMORY_SCOPE_AGENT);
            while (!__all(v >= (unsigned)TQ))
                v = __hip_atomic_load(pf, __ATOMIC_RELAXED,
                                      __HIP_MEMORY_SCOPE_AGENT);
        }
        const unsigned short* hl = hbuf + (size_t)bg * 16 * HQ;  // T even -> buffer 0
        float fb = fcb[0];
        #pragma unroll
        for (int r = 0; r < 2; ++r) {
            int b = w * 2 + r;
            float sacc = 0.f;
            #pragma unroll
            for (int j = 0; j < 16; ++j) {
                int u = j * 64 + lane;
                unsigned short hv = __hip_atomic_load(hl + (size_t)b * HQ + u,
                                                      __ATOMIC_RELAXED,
                                                      __HIP_MEMORY_SCOPE_AGENT);
                sacc += tanh_f(bf2f(hv)) * fcW[u];
            }
            #pragma unroll
            for (int off = 32; off > 0; off >>= 1)
                sacc += __shfl_down(sacc, off);
            if (lane == 0) out[bg * 16 + b] = sacc + fb;
        }
    }
}

extern "C" void kernel_launch(void* const* d_in, const int* in_sizes, int n_in,
                              void* d_out, int out_size, void* d_ws, size_t ws_size,
                              hipStream_t stream) {
    (void)in_sizes; (void)n_in; (void)out_size; (void)ws_size;
    const float* x   = (const float*)d_in[0];
    const float* Wih = (const float*)d_in[1];
    const float* Whh = (const float*)d_in[2];
    const float* bih = (const float*)d_in[3];
    const float* bhh = (const float*)d_in[4];
    const float* fcW = (const float*)d_in[5];
    const float* fcb = (const float*)d_in[6];
    float* out = (float*)d_out;

    unsigned short* hbuf = (unsigned short*)d_ws;                  // 262144 B
    unsigned int*   bar  = (unsigned int*)((char*)d_ws + 262144);  // 16384 B

    hipMemsetAsync(d_ws, 0, 262144 + 16384, stream);

    void* args[] = { &x, &Wih, &Whh, &bih, &bhh, &fcW, &fcb, &out, &hbuf, &bar };
    hipLaunchCooperativeKernel(reinterpret_cast<void*>(lstm_persist),
                               dim3(256), dim3(512), args, 0, stream);
}

// Round 6
// 2099.648 us; speedup vs baseline: 4.0013x; 1.0716x over previous
//
#include <hip/hip_runtime.h>
#include <hip/hip_bf16.h>

// LSTM: B=64, T=512, I=256, H=1024, O=1.
// Persistent cooperative kernel: 256 blocks = 4 batch-groups x 64 unit-groups.
// R10 = R9 with the consumer A-fragment address fixed (quad*8 term restored).
//  - bulk h loads: one global_load_dwordx4 sc0 sc1 (system-scope, 16B) per
//    lane per j instead of 2x8B agent atomics -> half the transactions at
//    the coherence point. waitcnt inside the asm block; "memory" clobber
//    keeps it ordered after the flag poll.
//  - 2x replication of h AND flags: producers store both copies; consumers
//    pick copy by (ug & 1). Halves per-line reader count (64 -> 32) at the
//    MALL, de-contending the slices the producer must also store through.
//  - Back-pressure: every block writes BOTH flag replicas; flag >= t+1 from
//    block Y still implies Y finished its step-t bulk reads (of its copy),
//    so overwriting both copies of buffer p^1 at step t+1 is safe. Same
//    argument as R4/R8.
//  - A-fragment layout reminder (16x16x32 bf16): lane = quad*16 + l16 holds
//    row l16, k = (chunk base) + quad*8 + {0..7}. The consumer base MUST
//    include quad*8 (R9's silent-wrong-answer bug).

typedef __bf16 bf16_t;
typedef bf16_t b16x8 __attribute__((ext_vector_type(8)));
typedef float  f32x4 __attribute__((ext_vector_type(4)));

#define TQ 512
#define IQ 256
#define HQ 1024

// partials: [w][g][u=16][b padded to 20] floats = 40960 B
#define RED(w,g,u,b) (((((w)*4 + (g))*16 + (u))*20) + (b))

// hbuf layout: [copy2][p2][bg4][b16][u1024] bf16
#define HCOPY 131072   // shorts per copy
#define HPBUF 65536    // shorts per p-buffer
// bar layout: [copy2][bg4][prod64][wave16] u32
#define BCOPY 4096     // u32 per copy

union U8 { b16x8 b; unsigned long long q[2]; unsigned short u[8]; };
union HU { f32x4 f; b16x8 b; };

__device__ __forceinline__ float bf2f(unsigned short s) {
    return __uint_as_float(((unsigned)s) << 16);
}
__device__ __forceinline__ unsigned short f2bf(float f) {
    unsigned u = __float_as_uint(f);
    u += 0x7fff + ((u >> 16) & 1);   // RNE
    return (unsigned short)(u >> 16);
}
__device__ __forceinline__ b16x8 cvt84(float4 a, float4 b) {
    U8 r;
    r.u[0] = f2bf(a.x); r.u[1] = f2bf(a.y); r.u[2] = f2bf(a.z); r.u[3] = f2bf(a.w);
    r.u[4] = f2bf(b.x); r.u[5] = f2bf(b.y); r.u[6] = f2bf(b.z); r.u[7] = f2bf(b.w);
    return r.b;
}
__device__ __forceinline__ float frcp(float x) { return __builtin_amdgcn_rcpf(x); }
__device__ __forceinline__ float sigm(float x) {
    return frcp(1.f + __expf(-x));
}
__device__ __forceinline__ float tanh_f(float v) {
    float x = fminf(fmaxf(v, -15.f), 15.f);
    float e = __expf(2.f * x);
    return (e - 1.f) * frcp(e + 1.f);
}

// 4 x 16B system-scope loads (k-chunks 64B apart) + waitcnt, all in one asm
// block: outputs are defined only at block end, so dependent MFMAs cannot be
// hoisted above the waitcnt; "memory" orders it after the flag-poll atomics.
__device__ __forceinline__ void load_h64_sys(b16x8* ah, const unsigned short* p0) {
    HU h0, h1, h2, h3;
    asm volatile(
        "global_load_dwordx4 %0, %4, off sc0 sc1\n\t"
        "global_load_dwordx4 %1, %4, off offset:64 sc0 sc1\n\t"
        "global_load_dwordx4 %2, %4, off offset:128 sc0 sc1\n\t"
        "global_load_dwordx4 %3, %4, off offset:192 sc0 sc1\n\t"
        "s_waitcnt vmcnt(0)"
        : "=&v"(h0.f), "=&v"(h1.f), "=&v"(h2.f), "=&v"(h3.f)
        : "v"(p0)
        : "memory");
    ah[0] = h0.b; ah[1] = h1.b; ah[2] = h2.b; ah[3] = h3.b;
}

__launch_bounds__(512, 2)
__global__ void lstm_persist(const float* __restrict__ x,
                             const float* __restrict__ Wih,
                             const float* __restrict__ Whh,
                             const float* __restrict__ bih,
                             const float* __restrict__ bhh,
                             const float* __restrict__ fcW,
                             const float* __restrict__ fcb,
                             float* __restrict__ out,
                             unsigned short* __restrict__ hbuf, // [2][2][4][16][1024] bf16
                             unsigned int* __restrict__ bar)    // [2][4][64][16] u32
{
    __shared__ float red[8 * 4 * 16 * 20];   // 40 KB, single-buffered

    const int tid  = threadIdx.x;
    const int w    = tid >> 6;        // wave 0..7
    const int lane = tid & 63;
    const int bid  = blockIdx.x;
    const int bg   = bid & 3;         // batch group (16 batches)
    const int ug   = bid >> 2;        // unit group (16 hidden units)
    const int par  = ug & 1;          // which replica this block READS

    const int l16  = lane & 15;
    const int quad = lane >> 4;

    // ---- one-time: load weight fragments into registers (bf16) ----
    b16x8 wih[4];        // x part: this wave's x-kstep
    b16x8 whh[4][4];     // h part: 4 ksteps x 4 gates
    {
        const int koff = quad * 8;
        #pragma unroll
        for (int g = 0; g < 4; ++g) {
            int row = g * HQ + ug * 16 + l16;
            const float* p = Wih + (size_t)row * IQ + w * 32 + koff;
            float4 a = *(const float4*)p;
            float4 b = *(const float4*)(p + 4);
            wih[g] = cvt84(a, b);
            #pragma unroll
            for (int j = 0; j < 4; ++j) {
                int k0 = (w * 4 + j) * 32 + koff;
                const float* q = Whh + (size_t)row * HQ + k0;
                float4 c = *(const float4*)q;
                float4 e = *(const float4*)(q + 4);
                whh[j][g] = cvt84(c, e);
            }
        }
    }

    // ---- epilogue lane assignment: (b = eb, u = l16), dup pairs xor-16 ----
    const int hi  = (lane >> 5) & 1;
    const int eb  = 2 * w + hi;          // batch row handled by this lane
    const int dup = (lane >> 4) & 1;     // partial-sum half (ww 0-3 vs 4-7)
    float c_st = 0.f;                    // cell state for (eb, u=l16)
    float bias_g[4];
    #pragma unroll
    for (int g = 0; g < 4; ++g) {
        int gr = g * HQ + ug * 16 + l16;
        bias_g[g] = bih[gr] + bhh[gr];
    }

    // consumer read base (its replica): row l16, this wave's K-chunk,
    // per-lane k-offset quad*8 (A-fragment layout — REQUIRED, see header)
    const unsigned short* hrd0 = hbuf + (size_t)par * HCOPY
                               + ((size_t)bg * 16 + l16) * HQ + w * 128 + quad * 8;
    // producer write base (copy 0); copy1 = +HCOPY
    unsigned short* hwr0 = hbuf + (size_t)bg * 16 * HQ + (size_t)eb * HQ + ug * 16 + l16;

    // flags: consumer polls its replica; producer writes both replicas
    const unsigned int* myfl = bar + (size_t)par * BCOPY
                             + ((size_t)(bg * 64 + w * 8 + (lane >> 3)) * 16 + (lane & 7));
    unsigned int* wfl0 = bar + ((size_t)(bg * 64 + ug) * 16 + w);
    unsigned int* wfl1 = wfl0 + BCOPY;

    // software-pipelined x load (step 0)
    const float* xbase = x + ((size_t)(bg * 16 + l16) * TQ) * IQ + w * 32 + quad * 8;
    float4 xa = *(const float4*)(xbase);
    float4 xb = *(const float4*)(xbase + 4);

    for (int t = 0; t < TQ; ++t) {
        const int p = t & 1;

        // ---- h-independent shadow work ----
        b16x8 ax = cvt84(xa, xb);
        f32x4 acc[4];
        #pragma unroll
        for (int g = 0; g < 4; ++g) {
            f32x4 z = {0.f, 0.f, 0.f, 0.f};
            acc[g] = __builtin_amdgcn_mfma_f32_16x16x32_bf16(ax, wih[g], z, 0, 0, 0);
        }

        // ---- poll this K-slice's 8 producers x 8 waves (64 lanes) ----
        const unsigned need = (unsigned)t;
        {
            unsigned v = __hip_atomic_load(myfl, __ATOMIC_RELAXED,
                                           __HIP_MEMORY_SCOPE_AGENT);
            while (!__all(v >= need))
                v = __hip_atomic_load(myfl, __ATOMIC_RELAXED,
                                      __HIP_MEMORY_SCOPE_AGENT);
        }

        // ---- h A-fragments (16B system-scope loads) + h MFMAs ----
        b16x8 ah[4];
        load_h64_sys(ah, hrd0 + (size_t)p * HPBUF);
        #pragma unroll
        for (int j = 0; j < 4; ++j) {
            #pragma unroll
            for (int g = 0; g < 4; ++g)
                acc[g] = __builtin_amdgcn_mfma_f32_16x16x32_bf16(ah[j], whh[j][g], acc[g], 0, 0, 0);
        }

        // ---- barrier A: previous step's epilogue reads are complete ----
        __syncthreads();

        // ---- write partials: one aligned ds_write_b128 per (lane, gate) ----
        #pragma unroll
        for (int g = 0; g < 4; ++g)
            *(f32x4*)&red[RED(w, g, l16, quad * 4)] = acc[g];
        __syncthreads();   // barrier B: partials visible to all waves

        // ---- parallel epilogue: all 8 waves, 2 batch rows each ----
        float s[4];
        #pragma unroll
        for (int g = 0; g < 4; ++g) {
            float a0 = red[RED(dup * 4 + 0, g, l16, eb)]
                     + red[RED(dup * 4 + 1, g, l16, eb)];
            float a1 = red[RED(dup * 4 + 2, g, l16, eb)]
                     + red[RED(dup * 4 + 3, g, l16, eb)];
            float as = a0 + a1;
            as += __shfl_xor(as, 16);      // combine dup halves
            s[g] = as;
        }
        {
            float gi = s[0] + bias_g[0];
            float gf = s[1] + bias_g[1];
            float gg = s[2] + bias_g[2];
            float go = s[3] + bias_g[3];
            float i_s = sigm(gi);
            float f_s = sigm(gf);
            float g_t = tanh_f(gg);
            float o_s = sigm(go);
            float c = f_s * c_st + i_s * g_t;
            c_st = c;
            float h = o_s * tanh_f(c);
            if (!dup) {
                unsigned short hv = f2bf(h);
                __hip_atomic_store(hwr0 + (size_t)(p ^ 1) * HPBUF, hv,
                                   __ATOMIC_RELAXED, __HIP_MEMORY_SCOPE_AGENT);
                __hip_atomic_store(hwr0 + HCOPY + (size_t)(p ^ 1) * HPBUF, hv,
                                   __ATOMIC_RELAXED, __HIP_MEMORY_SCOPE_AGENT);
            }
        }
        // per-wave drain (both copies) then both flag replicas
        asm volatile("s_waitcnt vmcnt(0)" ::: "memory");
        if (lane == 0) {
            __hip_atomic_store(wfl0, (unsigned)(t + 1),
                               __ATOMIC_RELAXED, __HIP_MEMORY_SCOPE_AGENT);
            __hip_atomic_store(wfl1, (unsigned)(t + 1),
                               __ATOMIC_RELAXED, __HIP_MEMORY_SCOPE_AGENT);
        }

        // x prefetch (after the drain so it doesn't extend it)
        size_t nt = (t + 1 < TQ) ? (size_t)(t + 1) * IQ : (size_t)t * IQ;
        xa = *(const float4*)(xbase + nt);
        xb = *(const float4*)(xbase + nt + 4);
    }

    // ---- final projection: out = tanh(h_T) @ fcW^T + fcb (blocks 0..3) ----
    if (bid < 4) {
        // wait for all 64 producers x 8 waves (copy-0 replica; all write it)
        #pragma unroll
        for (int pb = 0; pb < 8; ++pb) {
            const unsigned int* pf = bar + ((size_t)(bg * 64 + pb * 8 + (lane >> 3)) * 16 + (lane & 7));
            unsigned v = __hip_atomic_load(pf, __ATOMIC_RELAXED,
                                           __HIP_MEMORY_SCOPE_AGENT);
            while (!__all(v >= (unsigned)TQ))
                v = __hip_atomic_load(pf, __ATOMIC_RELAXED,
                                      __HIP_MEMORY_SCOPE_AGENT);
        }
        const unsigned short* hl = hbuf + (size_t)bg * 16 * HQ;  // copy0, T even -> buffer 0
        float fb = fcb[0];
        #pragma unroll
        for (int r = 0; r < 2; ++r) {
            int b = w * 2 + r;
            float sacc = 0.f;
            #pragma unroll
            for (int j = 0; j < 16; ++j) {
                int u = j * 64 + lane;
                unsigned short hv = __hip_atomic_load(hl + (size_t)b * HQ + u,
                                                      __ATOMIC_RELAXED,
                                                      __HIP_MEMORY_SCOPE_AGENT);
                sacc += tanh_f(bf2f(hv)) * fcW[u];
            }
            #pragma unroll
            for (int off = 32; off > 0; off >>= 1)
                sacc += __shfl_down(sacc, off);
            if (lane == 0) out[bg * 16 + b] = sacc + fb;
        }
    }
}

extern "C" void kernel_launch(void* const* d_in, const int* in_sizes, int n_in,
                              void* d_out, int out_size, void* d_ws, size_t ws_size,
                              hipStream_t stream) {
    (void)in_sizes; (void)n_in; (void)out_size; (void)ws_size;
    const float* x   = (const float*)d_in[0];
    const float* Wih = (const float*)d_in[1];
    const float* Whh = (const float*)d_in[2];
    const float* bih = (const float*)d_in[3];
    const float* bhh = (const float*)d_in[4];
    const float* fcW = (const float*)d_in[5];
    const float* fcb = (const float*)d_in[6];
    float* out = (float*)d_out;

    unsigned short* hbuf = (unsigned short*)d_ws;                  // 2 x 262144 B
    unsigned int*   bar  = (unsigned int*)((char*)d_ws + 524288);  // 2 x 16384 B

    hipMemsetAsync(d_ws, 0, 524288 + 32768, stream);

    void* args[] = { &x, &Wih, &Whh, &bih, &bhh, &fcW, &fcb, &out, &hbuf, &bar };
    hipLaunchCooperativeKernel(reinterpret_cast<void*>(lstm_persist),
                               dim3(256), dim3(512), args, 0, stream);
}